// Round 15
// baseline (205.905 us; speedup 1.0000x reference)
//
#include <hip/hip_runtime.h>
#include <hip/hip_bf16.h>

typedef __bf16 bf16x8 __attribute__((ext_vector_type(8)));
typedef float  f32x4  __attribute__((ext_vector_type(4)));
typedef float  f32x16 __attribute__((ext_vector_type(16)));

#define H_  20
#define S_  2048
#define D_  1280
#define HD_ 64
#define M_  4096

__device__ __forceinline__ unsigned short f2bf(float f) {
    union { float f; unsigned int u; } v; v.f = f;
    return (unsigned short)((v.u + 0x7FFFu + ((v.u >> 16) & 1u)) >> 16);
}

__device__ __forceinline__ unsigned short b2u(float f) {
    union { __bf16 b; unsigned short u; } v; v.b = (__bf16)f; return v.u;
}

// bare v_exp_f32 (libm exp2f is a ~15-instr libcall)
__device__ __forceinline__ float fexp2(float x) {
    return __builtin_amdgcn_exp2f(x);
}

// packed f32x2 -> bf16x2, single HW instr
__device__ __forceinline__ unsigned cvtpk(float lo, float hi) {
    unsigned r;
    asm("v_cvt_pk_bf16_f32 %0, %1, %2" : "=v"(r) : "v"(lo), "v"(hi));
    return r;
}

__device__ __forceinline__ void gll16(const void* g, void* l) {
    __builtin_amdgcn_global_load_lds(
        (const __attribute__((address_space(1))) unsigned int*)g,
        (__attribute__((address_space(3))) unsigned int*)l, 16, 0, 0);
}

// counted-vmcnt barrier (T4): leave N loads in flight, raw barrier (no drain).
#define WAIT_BAR(N) asm volatile("s_waitcnt vmcnt(" #N ")\n\ts_barrier" ::: "memory")

// attn LDS (128B rows, 8x16B granules): phys granule = g ^ (row&7)
#define SWZ(base, row, g) \
    (*(const bf16x8*)((base) + (row) * 64 + (((g) ^ ((row) & 7)) * 8)))

// gemm LDS (64B rows, 4x16B granules): phys granule = g ^ ((row>>1)&3)
#define SWZG(base, row, g) \
    (*(const bf16x8*)((base) + (row) * 32 + ((((g) ^ (((row) >> 1) & 3)) * 8))))

// ---------------- cast f32 -> bf16 (flat) ----------------
__global__ __launch_bounds__(256) void cast_bf16_kernel(
    const float* __restrict__ in, unsigned short* __restrict__ out, int n)
{
    int i = (blockIdx.x * 256 + threadIdx.x) * 4;
    if (i + 3 < n) {
        const float4 v = *(const float4*)(in + i);
        ushort4 o;
        o.x = f2bf(v.x); o.y = f2bf(v.y); o.z = f2bf(v.z); o.w = f2bf(v.w);
        *(ushort4*)(out + i) = o;
    }
}

// ---------------- transpose + cast for weights: Wt[n][k] = W[k][n] ----------------
__global__ __launch_bounds__(256) void transpose_cast_kernel(
    const float* __restrict__ W0, const float* __restrict__ W1,
    const float* __restrict__ W2, const float* __restrict__ W3,
    unsigned short* __restrict__ outbase)
{
    __shared__ unsigned short tile[64][65];
    const float* src = (blockIdx.z == 0) ? W0 : (blockIdx.z == 1) ? W1 :
                       (blockIdx.z == 2) ? W2 : W3;
    unsigned short* dst = outbase + (size_t)blockIdx.z * D_ * D_;
    int n0 = blockIdx.x * 64, k0 = blockIdx.y * 64;
    int tx = threadIdx.x & 63, ty = threadIdx.x >> 6;
#pragma unroll
    for (int i = 0; i < 16; ++i) {
        int row = ty * 16 + i;
        tile[row][tx] = f2bf(src[(size_t)(k0 + row) * D_ + n0 + tx]);
    }
    __syncthreads();
#pragma unroll
    for (int i = 0; i < 16; ++i) {
        int row = ty * 16 + i;
        dst[(size_t)(n0 + row) * D_ + k0 + tx] = tile[tx][row];
    }
}

// ---------------- 128x256 bf16 GEMM, C = A @ Bt^T  (Bt is [N][K]) ----------------
// 4 waves x (64x128) wave-tiles: 12 frag reads feed 32 MFMAs (2.67 MFMA/read,
// -33% LDS traffic vs 64x64) — the 128^2 version was LDS-read bound.
// Depth-2 prefetch, 3 LDS buffers (72KB), counted vmcnt(6) + raw barrier.
// Requires gridDim.y == 32. mode 3: f32 rowmajor + bias ; mode 4: fused QKV.
__global__ __launch_bounds__(256) void gemm_bf16(
    const unsigned short* __restrict__ A, const unsigned short* __restrict__ Bt,
    void* __restrict__ C0, void* __restrict__ C1, void* __restrict__ C2,
    const float* __restrict__ bias,
    int Kdim, int Ndim, int mode, float oscale)
{
    __shared__ unsigned short sh[36864];   // A0,A1,A2 @0 (4096 el each); B0,B1,B2 @12288 (8192 el each)
    const int t = threadIdx.x;
    const int wid = t >> 6, lane = t & 63;

    // XCD-bijective 2D sub-tile: 4 consecutive blocks share bx (B panel L2-hot),
    // each XCD owns 4 A-panels.
    const int lin = blockIdx.x + blockIdx.y * gridDim.x;
    const int xcd = lin & 7, q = lin >> 3;
    const int bx = q >> 2, by = xcd * 4 + (q & 3);

    const int m0 = by * 128, n0 = bx * 256;
    const int wm = (wid >> 1) * 64, wn = (wid & 1) * 128;
    const int ln15 = lane & 15, ln4 = lane >> 4;

    f32x4 acc[4][8];
#pragma unroll
    for (int i = 0; i < 4; ++i)
#pragma unroll
        for (int j = 0; j < 8; ++j) acc[i][j] = (f32x4){0.f, 0.f, 0.f, 0.f};

    const int r0 = t >> 2;                                   // staging row 0..63
    const int c0s = (((t & 3) ^ ((r0 >> 1) & 3)) * 8);       // inverse-swizzled src granule
    const unsigned short* Ab = A + (size_t)m0 * Kdim;
    const unsigned short* Bb = Bt + (size_t)n0 * Kdim;
    const int nk = Kdim >> 5;

#define STAGE_G(k0, Abuf, Bbuf)                                                        \
    do {                                                                               \
        gll16(Ab + (size_t)(r0) * Kdim + (k0) + c0s,       (Abuf) + wid * 512);        \
        gll16(Ab + (size_t)(64 + r0) * Kdim + (k0) + c0s,  (Abuf) + 2048 + wid * 512); \
        gll16(Bb + (size_t)(r0) * Kdim + (k0) + c0s,       (Bbuf) + wid * 512);        \
        gll16(Bb + (size_t)(64 + r0) * Kdim + (k0) + c0s,  (Bbuf) + 2048 + wid * 512); \
        gll16(Bb + (size_t)(128 + r0) * Kdim + (k0) + c0s, (Bbuf) + 4096 + wid * 512); \
        gll16(Bb + (size_t)(192 + r0) * Kdim + (k0) + c0s, (Bbuf) + 6144 + wid * 512); \
    } while (0)

    unsigned short *A0 = sh, *A1 = sh + 4096, *A2 = sh + 8192;
    unsigned short *B0 = sh + 12288, *B1 = sh + 20480, *B2 = sh + 28672;

    STAGE_G(0, A0, B0);
    STAGE_G(32, A1, B1);
    WAIT_BAR(6);

    for (int kk = 0; kk < nk; ++kk) {
        if (kk + 2 < nk) STAGE_G((kk + 2) << 5, A2, B2);

        bf16x8 af[4], bfr[8];
#pragma unroll
        for (int i = 0; i < 4; ++i) af[i]  = SWZG(A0, wm + i * 16 + ln15, ln4);
#pragma unroll
        for (int j = 0; j < 8; ++j) bfr[j] = SWZG(B0, wn + j * 16 + ln15, ln4);
#pragma unroll
        for (int i = 0; i < 4; ++i)
#pragma unroll
            for (int j = 0; j < 8; ++j)
                acc[i][j] = __builtin_amdgcn_mfma_f32_16x16x32_bf16(af[i], bfr[j], acc[i][j], 0, 0, 0);

        if (kk + 1 < nk) {
            if (kk + 2 < nk) WAIT_BAR(6);   // oldest 6 (next tile) landed; newest 6 fly on
            else             WAIT_BAR(0);   // tail drain
        }
        unsigned short* tA = A0; A0 = A1; A1 = A2; A2 = tA;
        unsigned short* tB = B0; B0 = B1; B1 = B2; B2 = tB;
    }
#undef STAGE_G

    // epilogue
#pragma unroll
    for (int i = 0; i < 4; ++i) {
#pragma unroll
        for (int j = 0; j < 8; ++j) {
            const int gmb = m0 + wm + i * 16 + ln4 * 4;
            const int gn  = n0 + wn + j * 16 + ln15;
#pragma unroll
            for (int r = 0; r < 4; ++r) {
                float val = acc[i][j][r];
                const int m = gmb + r;
                const int b = m >> 11, s = m & 2047;
                if (mode == 3) {
                    ((float*)C0)[(size_t)m * Ndim + gn] = val + bias[gn];
                } else {
                    const int which = gn / 1280;
                    const int nn = gn - which * 1280;
                    const int h = nn >> 6, d = nn & 63;
                    if (which == 0) val *= oscale;
                    size_t idx;
                    void* dst;
                    if (which == 2) { idx = ((size_t)(b * H_ + h) * HD_ + d) * S_ + s; dst = C2; }
                    else            { idx = ((size_t)(b * H_ + h) * S_ + s) * HD_ + d; dst = (which == 0) ? C0 : C1; }
                    ((unsigned short*)dst)[idx] = f2bf(val);
                }
            }
        }
    }
}

// ---------------- flash attention, swapped-operand 32x32, 4 waves x 32 q-rows ----------------
// R9's proven structure VERBATIM (76us, VGPR 80, occ 24%): 2 LDS buffers,
// scalar trees + __shfl_xor cross-half, defer-max, fexp2, cvt_pk+permlane pack.
// Two VALU-diet attempts (R5-vectors, R14 la-vectors) both lost by raising VGPR.
// NSPLIT=2: KV-split flash-decode, fp32 partials + (m,l). 32KB LDS.
template<int NSPLIT>
__global__ __launch_bounds__(256) void attn_kernel(
    const unsigned short* __restrict__ Q, const unsigned short* __restrict__ K,
    const unsigned short* __restrict__ V, unsigned short* __restrict__ O,
    float* __restrict__ Op, float* __restrict__ Ml)
{
    __shared__ unsigned short lds[16384];

    const int t = threadIdx.x, wid = t >> 6, lane = t & 63;
    const int ln31 = lane & 31, lhi = lane >> 5;

    // XCD-bijective swizzle -> 5 heads per XCD (K/V 2.5MB < 4MB L2)
    int qtile, bh, split;
    if constexpr (NSPLIT == 2) {
        const int lin = blockIdx.x + blockIdx.y * 32;     // 1280 wgs
        const int nl  = (lin & 7) * 160 + (lin >> 3);
        split = nl & 1; qtile = (nl >> 1) & 15; bh = nl >> 5;
    } else {
        const int lin = blockIdx.x + blockIdx.y * 16;     // 640 wgs
        const int nl  = (lin & 7) * 80 + (lin >> 3);
        split = 0; qtile = nl & 15; bh = nl >> 4;
    }

    const int q0 = qtile * 128;
    const int t00 = split * 1024;                         // first KV row of my half
    const int NT  = (NSPLIT == 2) ? 16 : 32;
    const unsigned short* Qh = Q + (size_t)bh * S_ * HD_;
    const unsigned short* Kh = K + (size_t)bh * S_ * HD_;
    const unsigned short* Vh = V + (size_t)bh * HD_ * S_;

    const int srow = t >> 3;                       // staging row 0..31 per issue
    const int scol = (((t & 7) ^ (srow & 7)) * 8); // inverse-swizzled source granule

    // ---- stage Q (128x64) into buf1 region ----
#pragma unroll
    for (int j = 0; j < 4; ++j)
        gll16(Qh + (size_t)(q0 + j * 32 + srow) * HD_ + scol,
              lds + 8192 + j * 2048 + wid * 512);
    __syncthreads();

    // Q B-operand frags: lane holds Q[q = wid*32+ln31][d = j*16 + lhi*8 + e]
    bf16x8 qf[4];
    {
        const int row = wid * 32 + ln31;
#pragma unroll
        for (int j = 0; j < 4; ++j)
            qf[j] = SWZ(lds + 8192, row, j * 2 + lhi);
    }

    // ---- stage KV tile 0 of my half into buf0 ----
    gll16(Kh + (size_t)(t00 + srow) * HD_ + scol,      lds + wid * 512);
    gll16(Kh + (size_t)(t00 + 32 + srow) * HD_ + scol, lds + 2048 + wid * 512);
    gll16(Vh + (size_t)srow * S_ + t00 + scol,         lds + 4096 + wid * 512);
    gll16(Vh + (size_t)(32 + srow) * S_ + t00 + scol,  lds + 4096 + 2048 + wid * 512);
    __syncthreads();   // drains KV0 loads AND all waves' Q ds_reads (pre-alias)

    // incrementing staging pointers (next tile)
    const unsigned short* Kp = Kh + (size_t)(t00 + 64 + srow) * HD_ + scol;
    const unsigned short* Vp = Vh + (size_t)srow * S_ + t00 + 64 + scol;

    f32x16 ot[2];
#pragma unroll
    for (int r = 0; r < 16; ++r) { ot[0][r] = 0.f; ot[1][r] = 0.f; }
    float m_ = -3.0e38f, l_ = 0.f;

    for (int it = 0; it < NT; ++it) {
        const unsigned short* cb = lds + (it & 1) * 8192;
        if (it + 1 < NT) {
            unsigned short* nb = lds + ((it + 1) & 1) * 8192;
            gll16(Kp,            nb + wid * 512);
            gll16(Kp + 32 * HD_, nb + 2048 + wid * 512);
            gll16(Vp,            nb + 4096 + wid * 512);
            gll16(Vp + 32 * S_,  nb + 4096 + 2048 + wid * 512);
            Kp += 64 * HD_;
            Vp += 64;
        }

        // ---- S^T = K Q^T : st[h] holds S[kt = h*32 + pat(r,lhi)][q = ln31] ----
        f32x16 st[2];
#pragma unroll
        for (int r = 0; r < 16; ++r) { st[0][r] = 0.f; st[1][r] = 0.f; }
        __builtin_amdgcn_s_setprio(1);
#pragma unroll
        for (int h = 0; h < 2; ++h) {
            const int row = h * 32 + ln31;
#pragma unroll
            for (int j = 0; j < 4; ++j) {
                const bf16x8 kf = SWZ(cb, row, j * 2 + lhi);
                st[h] = __builtin_amdgcn_mfma_f32_32x32x16_bf16(kf, qf[j], st[h], 0, 0, 0);
            }
        }
        __builtin_amdgcn_s_setprio(0);

        // ---- row max: scalar tree (max3-fusable) + cross-half shfl ----
        float t8[8];
#pragma unroll
        for (int i = 0; i < 8; ++i)
            t8[i] = fmaxf(fmaxf(st[0][i], st[0][i + 8]), fmaxf(st[1][i], st[1][i + 8]));
        const float ta = fmaxf(fmaxf(t8[0], t8[4]), fmaxf(t8[1], t8[5]));
        const float tb = fmaxf(fmaxf(t8[2], t8[6]), fmaxf(t8[3], t8[7]));
        float rm = fmaxf(ta, tb);
        rm = fmaxf(rm, __shfl_xor(rm, 32));   // both lanes of a q-row MUST agree on m_

        // ---- defer-max (T13) ----
        if (__any(rm - m_ > 8.0f)) {
            const float mn = fmaxf(m_, rm);
            const float sf = fexp2(m_ - mn);
            l_ *= sf;
#pragma unroll
            for (int r = 0; r < 16; ++r) { ot[0][r] *= sf; ot[1][r] *= sf; }
            m_ = mn;
        }

        // ---- P = exp2(S - m), in place (bare v_exp_f32) ----
#pragma unroll
        for (int r = 0; r < 16; ++r) {
            st[0][r] = fexp2(st[0][r] - m_);
            st[1][r] = fexp2(st[1][r] - m_);
        }

        // ---- sum: scalar tree + cross-half shfl ----
        {
            float s8[8];
#pragma unroll
            for (int i = 0; i < 8; ++i)
                s8[i] = (st[0][i] + st[0][i + 8]) + (st[1][i] + st[1][i + 8]);
#pragma unroll
            for (int i = 0; i < 4; ++i) s8[i] += s8[i + 4];
            float rs = (s8[0] + s8[1]) + (s8[2] + s8[3]);
            rs += __shfl_xor(rs, 32);
            l_ += rs;
        }

        // ---- pack P to bf16 frags in-register (T12): 16 cvt_pk + 8 permlane ----
        bf16x8 pa[4];
#pragma unroll
        for (int c = 0; c < 4; ++c) {
            const int hh = c >> 1, rb = (c & 1) * 8;
            const unsigned wA = cvtpk(st[hh][rb + 0], st[hh][rb + 1]);
            const unsigned wB = cvtpk(st[hh][rb + 2], st[hh][rb + 3]);
            const unsigned wC = cvtpk(st[hh][rb + 4], st[hh][rb + 5]);
            const unsigned wD = cvtpk(st[hh][rb + 6], st[hh][rb + 7]);
            auto s0 = __builtin_amdgcn_permlane32_swap(wA, wC, false, false);
            auto s1 = __builtin_amdgcn_permlane32_swap(wB, wD, false, false);
            union { unsigned i[4]; bf16x8 v; } u;
            u.i[0] = s0[0]; u.i[1] = s1[0]; u.i[2] = s0[1]; u.i[3] = s1[1];
            pa[c] = u.v;
        }

        // ---- O^T += V^T P : ot[h] holds O[dv = h*32 + pat(r,lhi)][q = ln31] ----
        __builtin_amdgcn_s_setprio(1);
#pragma unroll
        for (int h = 0; h < 2; ++h) {
            const int row = h * 32 + ln31;
#pragma unroll
            for (int c = 0; c < 4; ++c) {
                const bf16x8 vf = SWZ(cb + 4096, row, c * 2 + lhi);
                ot[h] = __builtin_amdgcn_mfma_f32_32x32x16_bf16(vf, pa[c], ot[h], 0, 0, 0);
            }
        }
        __builtin_amdgcn_s_setprio(0);

        __syncthreads();  // publishes prefetched tile, protects WAR
    }

    const int qg = q0 + wid * 32 + ln31;

    if constexpr (NSPLIT == 2) {
        // ---- write unnormalized fp32 partials + stats ----
        const size_t rowi = (size_t)(split * 40 + bh) * 2048 + qg;
        if (lhi == 0) {
            float2 s; s.x = m_; s.y = l_;
            ((float2*)Ml)[rowi] = s;
        }
        float* Orow = Op + rowi * 64;
#pragma unroll
        for (int h = 0; h < 2; ++h)
#pragma unroll
            for (int g = 0; g < 4; ++g) {
                f32x4 w = {ot[h][g * 4 + 0], ot[h][g * 4 + 1],
                           ot[h][g * 4 + 2], ot[h][g * 4 + 3]};
                *(f32x4*)(Orow + h * 32 + lhi * 4 + g * 8) = w;
            }
    } else {
        // ---- normalize, write O[b][s][h*64+dv] bf16 ----
        const int b = bh / H_, hh = bh % H_;
        const float inv = 1.0f / l_;
        unsigned short* Orow = O + (size_t)(b * S_ + qg) * D_ + hh * HD_;
#pragma unroll
        for (int h = 0; h < 2; ++h)
#pragma unroll
            for (int g = 0; g < 4; ++g) {
                ushort4 w;
                w.x = b2u(ot[h][g * 4 + 0] * inv);
                w.y = b2u(ot[h][g * 4 + 1] * inv);
                w.z = b2u(ot[h][g * 4 + 2] * inv);
                w.w = b2u(ot[h][g * 4 + 3] * inv);
                *(ushort4*)(Orow + h * 32 + lhi * 4 + g * 8) = w;
            }
    }
}

// ---------------- combine the two KV-split halves ----------------
__global__ __launch_bounds__(256) void attn_combine(
    const float* __restrict__ Op, const float* __restrict__ Ml,
    unsigned short* __restrict__ O)
{
    const int gid = blockIdx.x * 256 + threadIdx.x;
    const int row = gid >> 4;
    const int c   = (gid & 15) * 4;
    const int bh = row >> 11, qg = row & 2047;

    const float2 s0 = ((const float2*)Ml)[row];
    const float2 s1 = ((const float2*)Ml)[81920 + row];
    const float mm = fmaxf(s0.x, s1.x);
    const float a0 = fexp2(s0.x - mm), a1 = fexp2(s1.x - mm);
    const float inv = 1.0f / (a0 * s0.y + a1 * s1.y);

    const f32x4 o0 = *(const f32x4*)(Op + (size_t)row * 64 + c);
    const f32x4 o1 = *(const f32x4*)(Op + (size_t)(81920 + row) * 64 + c);

    const int b = bh / H_, hh = bh % H_;
    ushort4 w;
    w.x = b2u((a0 * o0[0] + a1 * o1[0]) * inv);
    w.y = b2u((a0 * o0[1] + a1 * o1[1]) * inv);
    w.z = b2u((a0 * o0[2] + a1 * o1[2]) * inv);
    w.w = b2u((a0 * o0[3] + a1 * o1[3]) * inv);
    *(ushort4*)(O + (size_t)(b * S_ + qg) * D_ + hh * HD_ + c) = w;
}

extern "C" void kernel_launch(void* const* d_in, const int* in_sizes, int n_in,
                              void* d_out, int out_size, void* d_ws, size_t ws_size,
                              hipStream_t stream)
{
    const float* hid = (const float*)d_in[0];
    const float* Wq  = (const float*)d_in[1];
    const float* Wk  = (const float*)d_in[2];
    const float* Wv  = (const float*)d_in[3];
    const float* Wo  = (const float*)d_in[4];
    const float* bo  = (const float*)d_in[5];
    float* out = (float*)d_out;

    char* ws = (char*)d_ws;
    unsigned short* Xb  = (unsigned short*)(ws);                    // 4096x1280 bf16
    unsigned short* Wt  = (unsigned short*)(ws + 10485760);         // 4x 1280x1280 bf16 (transposed)
    unsigned short* Qb  = (unsigned short*)(ws + 23592960);         // [b][h][s][64]
    unsigned short* Kb  = (unsigned short*)(ws + 34078720);         // [b][h][s][64]
    unsigned short* Vb  = (unsigned short*)(ws + 44564480);         // [b][h][64][s]
    unsigned short* Ob  = (unsigned short*)(ws + 55050240);         // [4096][1280]
    float*          Opart = (float*)(ws + 65536000);                // [2][40][2048][64] fp32
    float*          Mpart = (float*)(ws + 107479040);               // [2][40][2048] float2
    const size_t ws_need = 108789760ull;

    cast_bf16_kernel<<<5120, 256, 0, stream>>>(hid, Xb, M_ * D_);
    transpose_cast_kernel<<<dim3(20, 20, 4), 256, 0, stream>>>(Wq, Wk, Wv, Wo, Wt);

    const float SCALE_Q = 0.125f * 1.44269504088896340736f;  // sm_scale * log2(e)

    // fused QKV projection: Bt = [Wq^T; Wk^T; Wv^T] contiguous = [3840][1280]
    gemm_bf16<<<dim3(15, 32), 256, 0, stream>>>(Xb, Wt, Qb, Kb, Vb, nullptr,
                                                D_, 3840, 4, SCALE_Q);

    if (ws_size >= ws_need) {
        attn_kernel<2><<<dim3(32, 40), 256, 0, stream>>>(Qb, Kb, Vb, Ob, Opart, Mpart);
        attn_combine<<<5120, 256, 0, stream>>>(Opart, Mpart, Ob);
    } else {
        attn_kernel<1><<<dim3(16, 40), 256, 0, stream>>>(Qb, Kb, Vb, Ob, nullptr, nullptr);
    }

    gemm_bf16<<<dim3(5, 32), 256, 0, stream>>>(Ob, Wt + 3 * 1638400, out, nullptr, nullptr, bo,
                                               D_, D_, 3, 1.0f);
}

// Round 16
// 187.241 us; speedup vs baseline: 1.0997x; 1.0997x over previous
//
#include <hip/hip_runtime.h>
#include <hip/hip_bf16.h>

typedef __bf16 bf16x8 __attribute__((ext_vector_type(8)));
typedef float  f32x4  __attribute__((ext_vector_type(4)));
typedef float  f32x16 __attribute__((ext_vector_type(16)));

#define H_  20
#define S_  2048
#define D_  1280
#define HD_ 64
#define M_  4096

__device__ __forceinline__ unsigned short f2bf(float f) {
    union { float f; unsigned int u; } v; v.f = f;
    return (unsigned short)((v.u + 0x7FFFu + ((v.u >> 16) & 1u)) >> 16);
}

__device__ __forceinline__ unsigned short b2u(float f) {
    union { __bf16 b; unsigned short u; } v; v.b = (__bf16)f; return v.u;
}

// bare v_exp_f32 (libm exp2f is a ~15-instr libcall)
__device__ __forceinline__ float fexp2(float x) {
    return __builtin_amdgcn_exp2f(x);
}

// packed f32x2 -> bf16x2, single HW instr
__device__ __forceinline__ unsigned cvtpk(float lo, float hi) {
    unsigned r;
    asm("v_cvt_pk_bf16_f32 %0, %1, %2" : "=v"(r) : "v"(lo), "v"(hi));
    return r;
}

__device__ __forceinline__ void gll16(const void* g, void* l) {
    __builtin_amdgcn_global_load_lds(
        (const __attribute__((address_space(1))) unsigned int*)g,
        (__attribute__((address_space(3))) unsigned int*)l, 16, 0, 0);
}

// counted-vmcnt barrier (T4): leave N loads in flight, raw barrier (no drain).
#define WAIT_BAR(N) asm volatile("s_waitcnt vmcnt(" #N ")\n\ts_barrier" ::: "memory")

// attn LDS (128B rows, 8x16B granules): phys granule = g ^ (row&7)
#define SWZ(base, row, g) \
    (*(const bf16x8*)((base) + (row) * 64 + (((g) ^ ((row) & 7)) * 8)))

// gemm LDS (64B rows, 4x16B granules): phys granule = g ^ ((row>>1)&3)
#define SWZG(base, row, g) \
    (*(const bf16x8*)((base) + (row) * 32 + ((((g) ^ (((row) >> 1) & 3)) * 8))))

// ---------------- fused prep: cast X (blocks 0..5119) + transpose W (5120..6719) ----------------
// The two phases are independent; fusing them into one launch overlaps their
// memory traffic (they serialized on the stream before: ~8us + ~10us -> ~11us).
__global__ __launch_bounds__(256) void prep_kernel(
    const float* __restrict__ X, unsigned short* __restrict__ Xb,
    const float* __restrict__ W0, const float* __restrict__ W1,
    const float* __restrict__ W2, const float* __restrict__ W3,
    unsigned short* __restrict__ Wt)
{
    __shared__ unsigned short tile[64][65];
    const int blk = blockIdx.x;
    if (blk < 5120) {
        // cast f32 -> bf16, 4 el/thread
        const int i = (blk * 256 + threadIdx.x) * 4;
        const float4 v = *(const float4*)(X + i);
        ushort4 o;
        o.x = f2bf(v.x); o.y = f2bf(v.y); o.z = f2bf(v.z); o.w = f2bf(v.w);
        *(ushort4*)(Xb + i) = o;
    } else {
        // transpose+cast: 1600 blocks = 4 weights x (20 x 20) 64x64 tiles
        const int r = blk - 5120;
        const int wz = r / 400, rem = r - wz * 400;
        const int n0 = (rem % 20) * 64, k0 = (rem / 20) * 64;
        const float* src = (wz == 0) ? W0 : (wz == 1) ? W1 : (wz == 2) ? W2 : W3;
        unsigned short* dst = Wt + (size_t)wz * D_ * D_;
        const int tx = threadIdx.x & 63, ty = threadIdx.x >> 6;
#pragma unroll
        for (int i = 0; i < 16; ++i) {
            const int row = ty * 16 + i;
            tile[row][tx] = f2bf(src[(size_t)(k0 + row) * D_ + n0 + tx]);
        }
        __syncthreads();
#pragma unroll
        for (int i = 0; i < 16; ++i) {
            const int row = ty * 16 + i;
            dst[(size_t)(n0 + row) * D_ + k0 + tx] = tile[tx][row];
        }
    }
}

// ---------------- 128x128 bf16 GEMM, C = A @ Bt^T  (Bt is [N][K]) ----------------
// R9's proven shape: depth-2 prefetch, 3 LDS buffers (48KB), counted vmcnt(4).
// Requires gridDim.y == 32. mode 3: f32 rowmajor + bias ; mode 4: fused QKV.
__global__ __launch_bounds__(256) void gemm_bf16(
    const unsigned short* __restrict__ A, const unsigned short* __restrict__ Bt,
    void* __restrict__ C0, void* __restrict__ C1, void* __restrict__ C2,
    const float* __restrict__ bias,
    int Kdim, int Ndim, int mode, float oscale)
{
    __shared__ unsigned short sh[24576];   // A0,A1,A2 @0; B0,B1,B2 @12288 (48KB)
    const int t = threadIdx.x;
    const int wid = t >> 6, lane = t & 63;

    // XCD-bijective 2D sub-tile: 4 consecutive blocks share bx (B panel L2-hot),
    // each XCD owns 4 A-panels (1.3MB, L2-resident).
    const int lin = blockIdx.x + blockIdx.y * gridDim.x;
    const int xcd = lin & 7, q = lin >> 3;
    const int bx = q >> 2, by = xcd * 4 + (q & 3);

    const int m0 = by * 128, n0 = bx * 128;
    const int wm = (wid >> 1) * 64, wn = (wid & 1) * 64;
    const int ln15 = lane & 15, ln4 = lane >> 4;

    f32x4 acc[4][4];
#pragma unroll
    for (int i = 0; i < 4; ++i)
#pragma unroll
        for (int j = 0; j < 4; ++j) acc[i][j] = (f32x4){0.f, 0.f, 0.f, 0.f};

    const int r0 = t >> 2;                                   // staging row 0..63
    const int c0s = (((t & 3) ^ ((r0 >> 1) & 3)) * 8);       // inverse-swizzled src granule
    const unsigned short* Ab = A + (size_t)m0 * Kdim;
    const unsigned short* Bb = Bt + (size_t)n0 * Kdim;
    const int nk = Kdim >> 5;

#define STAGE_G(k0, Abuf, Bbuf)                                           \
    do {                                                                  \
        gll16(Ab + (size_t)(r0) * Kdim + (k0) + c0s,      (Abuf) + wid * 512);        \
        gll16(Ab + (size_t)(64 + r0) * Kdim + (k0) + c0s, (Abuf) + 2048 + wid * 512); \
        gll16(Bb + (size_t)(r0) * Kdim + (k0) + c0s,      (Bbuf) + wid * 512);        \
        gll16(Bb + (size_t)(64 + r0) * Kdim + (k0) + c0s, (Bbuf) + 2048 + wid * 512); \
    } while (0)

    unsigned short *A0 = sh, *A1 = sh + 4096, *A2 = sh + 8192;
    unsigned short *B0 = sh + 12288, *B1 = sh + 16384, *B2 = sh + 20480;

    STAGE_G(0, A0, B0);
    STAGE_G(32, A1, B1);
    WAIT_BAR(4);

    for (int kk = 0; kk < nk; ++kk) {
        if (kk + 2 < nk) STAGE_G((kk + 2) << 5, A2, B2);

        bf16x8 af[4], bfr[4];
#pragma unroll
        for (int i = 0; i < 4; ++i) af[i]  = SWZG(A0, wm + i * 16 + ln15, ln4);
#pragma unroll
        for (int i = 0; i < 4; ++i) bfr[i] = SWZG(B0, wn + i * 16 + ln15, ln4);
#pragma unroll
        for (int i = 0; i < 4; ++i)
#pragma unroll
            for (int j = 0; j < 4; ++j)
                acc[i][j] = __builtin_amdgcn_mfma_f32_16x16x32_bf16(af[i], bfr[j], acc[i][j], 0, 0, 0);

        if (kk + 1 < nk) {
            if (kk + 2 < nk) WAIT_BAR(4);
            else             WAIT_BAR(0);
        }
        unsigned short* tA = A0; A0 = A1; A1 = A2; A2 = tA;
        unsigned short* tB = B0; B0 = B1; B1 = B2; B2 = tB;
    }
#undef STAGE_G

    // epilogue
#pragma unroll
    for (int i = 0; i < 4; ++i) {
#pragma unroll
        for (int j = 0; j < 4; ++j) {
            const int gmb = m0 + wm + i * 16 + ln4 * 4;
            const int gn  = n0 + wn + j * 16 + ln15;
#pragma unroll
            for (int r = 0; r < 4; ++r) {
                float val = acc[i][j][r];
                const int m = gmb + r;
                const int b = m >> 11, s = m & 2047;
                if (mode == 3) {
                    ((float*)C0)[(size_t)m * Ndim + gn] = val + bias[gn];
                } else {
                    const int which = gn / 1280;
                    const int nn = gn - which * 1280;
                    const int h = nn >> 6, d = nn & 63;
                    if (which == 0) val *= oscale;
                    size_t idx;
                    void* dst;
                    if (which == 2) { idx = ((size_t)(b * H_ + h) * HD_ + d) * S_ + s; dst = C2; }
                    else            { idx = ((size_t)(b * H_ + h) * S_ + s) * HD_ + d; dst = (which == 0) ? C0 : C1; }
                    ((unsigned short*)dst)[idx] = f2bf(val);
                }
            }
        }
    }
}

// ---------------- flash attention, swapped-operand 32x32, 4 waves x 32 q-rows ----------------
// R9's proven structure VERBATIM (76us, VGPR 80, occ 24%): 2 LDS buffers,
// scalar trees + __shfl_xor cross-half, defer-max, fexp2, cvt_pk+permlane pack.
// VALU-diet attempts that raise VGPR (R5, R14) and bigger tiles (R15 gemm) all
// lost: these kernels are latency-bound — occupancy is the binding resource.
// NSPLIT=2: KV-split flash-decode, fp32 partials + (m,l). 32KB LDS.
template<int NSPLIT>
__global__ __launch_bounds__(256) void attn_kernel(
    const unsigned short* __restrict__ Q, const unsigned short* __restrict__ K,
    const unsigned short* __restrict__ V, unsigned short* __restrict__ O,
    float* __restrict__ Op, float* __restrict__ Ml)
{
    __shared__ unsigned short lds[16384];

    const int t = threadIdx.x, wid = t >> 6, lane = t & 63;
    const int ln31 = lane & 31, lhi = lane >> 5;

    // XCD-bijective swizzle -> 5 heads per XCD (K/V 2.5MB < 4MB L2)
    int qtile, bh, split;
    if constexpr (NSPLIT == 2) {
        const int lin = blockIdx.x + blockIdx.y * 32;     // 1280 wgs
        const int nl  = (lin & 7) * 160 + (lin >> 3);
        split = nl & 1; qtile = (nl >> 1) & 15; bh = nl >> 5;
    } else {
        const int lin = blockIdx.x + blockIdx.y * 16;     // 640 wgs
        const int nl  = (lin & 7) * 80 + (lin >> 3);
        split = 0; qtile = nl & 15; bh = nl >> 4;
    }

    const int q0 = qtile * 128;
    const int t00 = split * 1024;                         // first KV row of my half
    const int NT  = (NSPLIT == 2) ? 16 : 32;
    const unsigned short* Qh = Q + (size_t)bh * S_ * HD_;
    const unsigned short* Kh = K + (size_t)bh * S_ * HD_;
    const unsigned short* Vh = V + (size_t)bh * HD_ * S_;

    const int srow = t >> 3;                       // staging row 0..31 per issue
    const int scol = (((t & 7) ^ (srow & 7)) * 8); // inverse-swizzled source granule

    // ---- stage Q (128x64) into buf1 region ----
#pragma unroll
    for (int j = 0; j < 4; ++j)
        gll16(Qh + (size_t)(q0 + j * 32 + srow) * HD_ + scol,
              lds + 8192 + j * 2048 + wid * 512);
    __syncthreads();

    // Q B-operand frags: lane holds Q[q = wid*32+ln31][d = j*16 + lhi*8 + e]
    bf16x8 qf[4];
    {
        const int row = wid * 32 + ln31;
#pragma unroll
        for (int j = 0; j < 4; ++j)
            qf[j] = SWZ(lds + 8192, row, j * 2 + lhi);
    }

    // ---- stage KV tile 0 of my half into buf0 ----
    gll16(Kh + (size_t)(t00 + srow) * HD_ + scol,      lds + wid * 512);
    gll16(Kh + (size_t)(t00 + 32 + srow) * HD_ + scol, lds + 2048 + wid * 512);
    gll16(Vh + (size_t)srow * S_ + t00 + scol,         lds + 4096 + wid * 512);
    gll16(Vh + (size_t)(32 + srow) * S_ + t00 + scol,  lds + 4096 + 2048 + wid * 512);
    __syncthreads();   // drains KV0 loads AND all waves' Q ds_reads (pre-alias)

    // incrementing staging pointers (next tile)
    const unsigned short* Kp = Kh + (size_t)(t00 + 64 + srow) * HD_ + scol;
    const unsigned short* Vp = Vh + (size_t)srow * S_ + t00 + 64 + scol;

    f32x16 ot[2];
#pragma unroll
    for (int r = 0; r < 16; ++r) { ot[0][r] = 0.f; ot[1][r] = 0.f; }
    float m_ = -3.0e38f, l_ = 0.f;

    for (int it = 0; it < NT; ++it) {
        const unsigned short* cb = lds + (it & 1) * 8192;
        if (it + 1 < NT) {
            unsigned short* nb = lds + ((it + 1) & 1) * 8192;
            gll16(Kp,            nb + wid * 512);
            gll16(Kp + 32 * HD_, nb + 2048 + wid * 512);
            gll16(Vp,            nb + 4096 + wid * 512);
            gll16(Vp + 32 * S_,  nb + 4096 + 2048 + wid * 512);
            Kp += 64 * HD_;
            Vp += 64;
        }

        // ---- S^T = K Q^T : st[h] holds S[kt = h*32 + pat(r,lhi)][q = ln31] ----
        f32x16 st[2];
#pragma unroll
        for (int r = 0; r < 16; ++r) { st[0][r] = 0.f; st[1][r] = 0.f; }
        __builtin_amdgcn_s_setprio(1);
#pragma unroll
        for (int h = 0; h < 2; ++h) {
            const int row = h * 32 + ln31;
#pragma unroll
            for (int j = 0; j < 4; ++j) {
                const bf16x8 kf = SWZ(cb, row, j * 2 + lhi);
                st[h] = __builtin_amdgcn_mfma_f32_32x32x16_bf16(kf, qf[j], st[h], 0, 0, 0);
            }
        }
        __builtin_amdgcn_s_setprio(0);

        // ---- row max: scalar tree (max3-fusable) + cross-half shfl ----
        float t8[8];
#pragma unroll
        for (int i = 0; i < 8; ++i)
            t8[i] = fmaxf(fmaxf(st[0][i], st[0][i + 8]), fmaxf(st[1][i], st[1][i + 8]));
        const float ta = fmaxf(fmaxf(t8[0], t8[4]), fmaxf(t8[1], t8[5]));
        const float tb = fmaxf(fmaxf(t8[2], t8[6]), fmaxf(t8[3], t8[7]));
        float rm = fmaxf(ta, tb);
        rm = fmaxf(rm, __shfl_xor(rm, 32));   // both lanes of a q-row MUST agree on m_

        // ---- defer-max (T13) ----
        if (__any(rm - m_ > 8.0f)) {
            const float mn = fmaxf(m_, rm);
            const float sf = fexp2(m_ - mn);
            l_ *= sf;
#pragma unroll
            for (int r = 0; r < 16; ++r) { ot[0][r] *= sf; ot[1][r] *= sf; }
            m_ = mn;
        }

        // ---- P = exp2(S - m), in place (bare v_exp_f32) ----
#pragma unroll
        for (int r = 0; r < 16; ++r) {
            st[0][r] = fexp2(st[0][r] - m_);
            st[1][r] = fexp2(st[1][r] - m_);
        }

        // ---- sum: scalar tree + cross-half shfl ----
        {
            float s8[8];
#pragma unroll
            for (int i = 0; i < 8; ++i)
                s8[i] = (st[0][i] + st[0][i + 8]) + (st[1][i] + st[1][i + 8]);
#pragma unroll
            for (int i = 0; i < 4; ++i) s8[i] += s8[i + 4];
            float rs = (s8[0] + s8[1]) + (s8[2] + s8[3]);
            rs += __shfl_xor(rs, 32);
            l_ += rs;
        }

        // ---- pack P to bf16 frags in-register (T12): 16 cvt_pk + 8 permlane ----
        bf16x8 pa[4];
#pragma unroll
        for (int c = 0; c < 4; ++c) {
            const int hh = c >> 1, rb = (c & 1) * 8;
            const unsigned wA = cvtpk(st[hh][rb + 0], st[hh][rb + 1]);
            const unsigned wB = cvtpk(st[hh][rb + 2], st[hh][rb + 3]);
            const unsigned wC = cvtpk(st[hh][rb + 4], st[hh][rb + 5]);
            const unsigned wD = cvtpk(st[hh][rb + 6], st[hh][rb + 7]);
            auto s0 = __builtin_amdgcn_permlane32_swap(wA, wC, false, false);
            auto s1 = __builtin_amdgcn_permlane32_swap(wB, wD, false, false);
            union { unsigned i[4]; bf16x8 v; } u;
            u.i[0] = s0[0]; u.i[1] = s1[0]; u.i[2] = s0[1]; u.i[3] = s1[1];
            pa[c] = u.v;
        }

        // ---- O^T += V^T P : ot[h] holds O[dv = h*32 + pat(r,lhi)][q = ln31] ----
        __builtin_amdgcn_s_setprio(1);
#pragma unroll
        for (int h = 0; h < 2; ++h) {
            const int row = h * 32 + ln31;
#pragma unroll
            for (int c = 0; c < 4; ++c) {
                const bf16x8 vf = SWZ(cb + 4096, row, c * 2 + lhi);
                ot[h] = __builtin_amdgcn_mfma_f32_32x32x16_bf16(vf, pa[c], ot[h], 0, 0, 0);
            }
        }
        __builtin_amdgcn_s_setprio(0);

        __syncthreads();  // publishes prefetched tile, protects WAR
    }

    const int qg = q0 + wid * 32 + ln31;

    if constexpr (NSPLIT == 2) {
        // ---- write unnormalized fp32 partials + stats ----
        const size_t rowi = (size_t)(split * 40 + bh) * 2048 + qg;
        if (lhi == 0) {
            float2 s; s.x = m_; s.y = l_;
            ((float2*)Ml)[rowi] = s;
        }
        float* Orow = Op + rowi * 64;
#pragma unroll
        for (int h = 0; h < 2; ++h)
#pragma unroll
            for (int g = 0; g < 4; ++g) {
                f32x4 w = {ot[h][g * 4 + 0], ot[h][g * 4 + 1],
                           ot[h][g * 4 + 2], ot[h][g * 4 + 3]};
                *(f32x4*)(Orow + h * 32 + lhi * 4 + g * 8) = w;
            }
    } else {
        // ---- normalize, write O[b][s][h*64+dv] bf16 ----
        const int b = bh / H_, hh = bh % H_;
        const float inv = 1.0f / l_;
        unsigned short* Orow = O + (size_t)(b * S_ + qg) * D_ + hh * HD_;
#pragma unroll
        for (int h = 0; h < 2; ++h)
#pragma unroll
            for (int g = 0; g < 4; ++g) {
                ushort4 w;
                w.x = b2u(ot[h][g * 4 + 0] * inv);
                w.y = b2u(ot[h][g * 4 + 1] * inv);
                w.z = b2u(ot[h][g * 4 + 2] * inv);
                w.w = b2u(ot[h][g * 4 + 3] * inv);
                *(ushort4*)(Orow + h * 32 + lhi * 4 + g * 8) = w;
            }
    }
}

// ---------------- combine the two KV-split halves ----------------
__global__ __launch_bounds__(256) void attn_combine(
    const float* __restrict__ Op, const float* __restrict__ Ml,
    unsigned short* __restrict__ O)
{
    const int gid = blockIdx.x * 256 + threadIdx.x;
    const int row = gid >> 4;
    const int c   = (gid & 15) * 4;
    const int bh = row >> 11, qg = row & 2047;

    const float2 s0 = ((const float2*)Ml)[row];
    const float2 s1 = ((const float2*)Ml)[81920 + row];
    const float mm = fmaxf(s0.x, s1.x);
    const float a0 = fexp2(s0.x - mm), a1 = fexp2(s1.x - mm);
    const float inv = 1.0f / (a0 * s0.y + a1 * s1.y);

    const f32x4 o0 = *(const f32x4*)(Op + (size_t)row * 64 + c);
    const f32x4 o1 = *(const f32x4*)(Op + (size_t)(81920 + row) * 64 + c);

    const int b = bh / H_, hh = bh % H_;
    ushort4 w;
    w.x = b2u((a0 * o0[0] + a1 * o1[0]) * inv);
    w.y = b2u((a0 * o0[1] + a1 * o1[1]) * inv);
    w.z = b2u((a0 * o0[2] + a1 * o1[2]) * inv);
    w.w = b2u((a0 * o0[3] + a1 * o1[3]) * inv);
    *(ushort4*)(O + (size_t)(b * S_ + qg) * D_ + hh * HD_ + c) = w;
}

extern "C" void kernel_launch(void* const* d_in, const int* in_sizes, int n_in,
                              void* d_out, int out_size, void* d_ws, size_t ws_size,
                              hipStream_t stream)
{
    const float* hid = (const float*)d_in[0];
    const float* Wq  = (const float*)d_in[1];
    const float* Wk  = (const float*)d_in[2];
    const float* Wv  = (const float*)d_in[3];
    const float* Wo  = (const float*)d_in[4];
    const float* bo  = (const float*)d_in[5];
    float* out = (float*)d_out;

    char* ws = (char*)d_ws;
    unsigned short* Xb  = (unsigned short*)(ws);                    // 4096x1280 bf16
    unsigned short* Wt  = (unsigned short*)(ws + 10485760);         // 4x 1280x1280 bf16 (transposed)
    unsigned short* Qb  = (unsigned short*)(ws + 23592960);         // [b][h][s][64]
    unsigned short* Kb  = (unsigned short*)(ws + 34078720);         // [b][h][s][64]
    unsigned short* Vb  = (unsigned short*)(ws + 44564480);         // [b][h][64][s]
    unsigned short* Ob  = (unsigned short*)(ws + 55050240);         // [4096][1280]
    float*          Opart = (float*)(ws + 65536000);                // [2][40][2048][64] fp32
    float*          Mpart = (float*)(ws + 107479040);               // [2][40][2048] float2
    const size_t ws_need = 108789760ull;

    // fused cast + weight-transpose prep (phases overlap in one launch)
    prep_kernel<<<6720, 256, 0, stream>>>(hid, Xb, Wq, Wk, Wv, Wo, Wt);

    const float SCALE_Q = 0.125f * 1.44269504088896340736f;  // sm_scale * log2(e)

    // fused QKV projection: Bt = [Wq^T; Wk^T; Wv^T] contiguous = [3840][1280]
    gemm_bf16<<<dim3(30, 32), 256, 0, stream>>>(Xb, Wt, Qb, Kb, Vb, nullptr,
                                                D_, 3840, 4, SCALE_Q);

    if (ws_size >= ws_need) {
        attn_kernel<2><<<dim3(32, 40), 256, 0, stream>>>(Qb, Kb, Vb, Ob, Opart, Mpart);
        attn_combine<<<5120, 256, 0, stream>>>(Opart, Mpart, Ob);
    } else {
        attn_kernel<1><<<dim3(16, 40), 256, 0, stream>>>(Qb, Kb, Vb, Ob, nullptr, nullptr);
    }

    gemm_bf16<<<dim3(10, 32), 256, 0, stream>>>(Ob, Wt + 3 * 1638400, out, nullptr, nullptr, bo,
                                                D_, D_, 3, 1.0f);
}

// Round 17
// 172.064 us; speedup vs baseline: 1.1967x; 1.0882x over previous
//
#include <hip/hip_runtime.h>
#include <hip/hip_bf16.h>

typedef __bf16 bf16x8 __attribute__((ext_vector_type(8)));
typedef float  f32x4  __attribute__((ext_vector_type(4)));
typedef float  f32x16 __attribute__((ext_vector_type(16)));

#define H_  20
#define S_  2048
#define D_  1280
#define HD_ 64
#define M_  4096

__device__ __forceinline__ unsigned short f2bf(float f) {
    union { float f; unsigned int u; } v; v.f = f;
    return (unsigned short)((v.u + 0x7FFFu + ((v.u >> 16) & 1u)) >> 16);
}

__device__ __forceinline__ unsigned short b2u(float f) {
    union { __bf16 b; unsigned short u; } v; v.b = (__bf16)f; return v.u;
}

// bare v_exp_f32 (libm exp2f is a ~15-instr libcall)
__device__ __forceinline__ float fexp2(float x) {
    return __builtin_amdgcn_exp2f(x);
}

// packed f32x2 -> bf16x2, single HW instr
__device__ __forceinline__ unsigned cvtpk(float lo, float hi) {
    unsigned r;
    asm("v_cvt_pk_bf16_f32 %0, %1, %2" : "=v"(r) : "v"(lo), "v"(hi));
    return r;
}

__device__ __forceinline__ void gll16(const void* g, void* l) {
    __builtin_amdgcn_global_load_lds(
        (const __attribute__((address_space(1))) unsigned int*)g,
        (__attribute__((address_space(3))) unsigned int*)l, 16, 0, 0);
}

// counted-vmcnt barrier (T4): leave N loads in flight, raw barrier (no drain).
#define WAIT_BAR(N) asm volatile("s_waitcnt vmcnt(" #N ")\n\ts_barrier" ::: "memory")

// attn LDS (128B rows, 8x16B granules): phys granule = g ^ (row&7)
#define SWZ(base, row, g) \
    (*(const bf16x8*)((base) + (row) * 64 + (((g) ^ ((row) & 7)) * 8)))

// gemm LDS (64B rows, 4x16B granules): phys granule = g ^ ((row>>1)&3)
#define SWZG(base, row, g) \
    (*(const bf16x8*)((base) + (row) * 32 + ((((g) ^ (((row) >> 1) & 3)) * 8))))

// ---------------- fused prep: cast X (blocks 0..5119) + transpose W (5120..6719) ----------------
__global__ __launch_bounds__(256) void prep_kernel(
    const float* __restrict__ X, unsigned short* __restrict__ Xb,
    const float* __restrict__ W0, const float* __restrict__ W1,
    const float* __restrict__ W2, const float* __restrict__ W3,
    unsigned short* __restrict__ Wt)
{
    __shared__ unsigned short tile[64][65];
    const int blk = blockIdx.x;
    if (blk < 5120) {
        const int i = (blk * 256 + threadIdx.x) * 4;
        const float4 v = *(const float4*)(X + i);
        ushort4 o;
        o.x = f2bf(v.x); o.y = f2bf(v.y); o.z = f2bf(v.z); o.w = f2bf(v.w);
        *(ushort4*)(Xb + i) = o;
    } else {
        const int r = blk - 5120;
        const int wz = r / 400, rem = r - wz * 400;
        const int n0 = (rem % 20) * 64, k0 = (rem / 20) * 64;
        const float* src = (wz == 0) ? W0 : (wz == 1) ? W1 : (wz == 2) ? W2 : W3;
        unsigned short* dst = Wt + (size_t)wz * D_ * D_;
        const int tx = threadIdx.x & 63, ty = threadIdx.x >> 6;
#pragma unroll
        for (int i = 0; i < 16; ++i) {
            const int row = ty * 16 + i;
            tile[row][tx] = f2bf(src[(size_t)(k0 + row) * D_ + n0 + tx]);
        }
        __syncthreads();
#pragma unroll
        for (int i = 0; i < 16; ++i) {
            const int row = ty * 16 + i;
            dst[(size_t)(n0 + row) * D_ + k0 + tx] = tile[tx][row];
        }
    }
}

// ---------------- 256x128 QKV GEMM, 8 waves: {Q scaled, K, Vt} epilogue ----------------
// One scheduling round (480 blocks <= 2/CU x 256), 16 waves/CU, 3-buffer
// counted-vmcnt pipeline (3 gll16/step, WAIT_BAR(3)). Per-wave 64x64 acc[4][4].
__global__ __launch_bounds__(512) void gemm_qkv(
    const unsigned short* __restrict__ A, const unsigned short* __restrict__ Bt,
    unsigned short* __restrict__ C0, unsigned short* __restrict__ C1,
    unsigned short* __restrict__ C2, int Kdim, float oscale)
{
    __shared__ unsigned short sh[36864];  // A0,A1,A2 @0 (8192 el each); B0,B1,B2 @24576 (4096 el each)
    const int t = threadIdx.x;
    const int wid = t >> 6, lane = t & 63;

    // XCD-bijective: 480 wgs -> 60/XCD; by = xcd*2 + (q&1) (2 M-panels/XCD),
    // consecutive q pairs share bx (B panel L2-hot).
    const int lin = blockIdx.x + blockIdx.y * gridDim.x;
    const int xcd = lin & 7, q = lin >> 3;              // q 0..59
    const int bx = q >> 1, by = xcd * 2 + (q & 1);      // bx 0..29, by 0..15

    const int m0 = by * 256, n0 = bx * 128;
    const int wm = (wid >> 1) * 64, wn = (wid & 1) * 64;
    const int ln15 = lane & 15, ln4 = lane >> 4;

    f32x4 acc[4][4];
#pragma unroll
    for (int i = 0; i < 4; ++i)
#pragma unroll
        for (int j = 0; j < 4; ++j) acc[i][j] = (f32x4){0.f, 0.f, 0.f, 0.f};

    const int r0 = t >> 2;                                   // staging row 0..127
    const int c0s = (((t & 3) ^ ((r0 >> 1) & 3)) * 8);       // inverse-swizzled src granule
    const unsigned short* Ab = A + (size_t)m0 * Kdim;
    const unsigned short* Bb = Bt + (size_t)n0 * Kdim;
    const int nk = Kdim >> 5;

#define STAGE_Q(k0, Abuf, Bbuf)                                                        \
    do {                                                                               \
        gll16(Ab + (size_t)(r0) * Kdim + (k0) + c0s,       (Abuf) + wid * 512);        \
        gll16(Ab + (size_t)(128 + r0) * Kdim + (k0) + c0s, (Abuf) + 4096 + wid * 512); \
        gll16(Bb + (size_t)(r0) * Kdim + (k0) + c0s,       (Bbuf) + wid * 512);        \
    } while (0)

    unsigned short *A0 = sh, *A1 = sh + 8192, *A2 = sh + 16384;
    unsigned short *B0 = sh + 24576, *B1 = sh + 28672, *B2 = sh + 32768;

    STAGE_Q(0, A0, B0);
    STAGE_Q(32, A1, B1);
    WAIT_BAR(3);

    for (int kk = 0; kk < nk; ++kk) {
        if (kk + 2 < nk) STAGE_Q((kk + 2) << 5, A2, B2);

        bf16x8 af[4], bfr[4];
#pragma unroll
        for (int i = 0; i < 4; ++i) af[i]  = SWZG(A0, wm + i * 16 + ln15, ln4);
#pragma unroll
        for (int i = 0; i < 4; ++i) bfr[i] = SWZG(B0, wn + i * 16 + ln15, ln4);
#pragma unroll
        for (int i = 0; i < 4; ++i)
#pragma unroll
            for (int j = 0; j < 4; ++j)
                acc[i][j] = __builtin_amdgcn_mfma_f32_16x16x32_bf16(af[i], bfr[j], acc[i][j], 0, 0, 0);

        if (kk + 1 < nk) {
            if (kk + 2 < nk) WAIT_BAR(3);   // oldest 3 (next tile) landed; newest 3 fly on
            else             WAIT_BAR(0);   // tail drain
        }
        unsigned short* tA = A0; A0 = A1; A1 = A2; A2 = tA;
        unsigned short* tB = B0; B0 = B1; B1 = B2; B2 = tB;
    }
#undef STAGE_Q

    // epilogue: fused QKV scatter
#pragma unroll
    for (int i = 0; i < 4; ++i) {
#pragma unroll
        for (int j = 0; j < 4; ++j) {
            const int gmb = m0 + wm + i * 16 + ln4 * 4;
            const int gn  = n0 + wn + j * 16 + ln15;
            const int which = gn / 1280;
            const int nn = gn - which * 1280;
            const int h = nn >> 6, d = nn & 63;
#pragma unroll
            for (int r = 0; r < 4; ++r) {
                float val = acc[i][j][r];
                const int m = gmb + r;
                const int b = m >> 11, s = m & 2047;
                if (which == 0) val *= oscale;
                size_t idx;
                unsigned short* dst;
                if (which == 2) { idx = ((size_t)(b * H_ + h) * HD_ + d) * S_ + s; dst = C2; }
                else            { idx = ((size_t)(b * H_ + h) * S_ + s) * HD_ + d; dst = (which == 0) ? C0 : C1; }
                dst[idx] = f2bf(val);
            }
        }
    }
}

// ---------------- 128x128 bf16 GEMM (final projection, mode-3 f32 + bias) ----------------
// R9's proven shape: depth-2 prefetch, 3 LDS buffers (48KB), counted vmcnt(4).
__global__ __launch_bounds__(256) void gemm_bf16(
    const unsigned short* __restrict__ A, const unsigned short* __restrict__ Bt,
    float* __restrict__ C0, const float* __restrict__ bias, int Kdim, int Ndim)
{
    __shared__ unsigned short sh[24576];   // A0,A1,A2 @0; B0,B1,B2 @12288 (48KB)
    const int t = threadIdx.x;
    const int wid = t >> 6, lane = t & 63;

    const int lin = blockIdx.x + blockIdx.y * gridDim.x;
    const int xcd = lin & 7, q = lin >> 3;
    const int bx = q >> 2, by = xcd * 4 + (q & 3);

    const int m0 = by * 128, n0 = bx * 128;
    const int wm = (wid >> 1) * 64, wn = (wid & 1) * 64;
    const int ln15 = lane & 15, ln4 = lane >> 4;

    f32x4 acc[4][4];
#pragma unroll
    for (int i = 0; i < 4; ++i)
#pragma unroll
        for (int j = 0; j < 4; ++j) acc[i][j] = (f32x4){0.f, 0.f, 0.f, 0.f};

    const int r0 = t >> 2;                                   // staging row 0..63
    const int c0s = (((t & 3) ^ ((r0 >> 1) & 3)) * 8);       // inverse-swizzled src granule
    const unsigned short* Ab = A + (size_t)m0 * Kdim;
    const unsigned short* Bb = Bt + (size_t)n0 * Kdim;
    const int nk = Kdim >> 5;

#define STAGE_G(k0, Abuf, Bbuf)                                           \
    do {                                                                  \
        gll16(Ab + (size_t)(r0) * Kdim + (k0) + c0s,      (Abuf) + wid * 512);        \
        gll16(Ab + (size_t)(64 + r0) * Kdim + (k0) + c0s, (Abuf) + 2048 + wid * 512); \
        gll16(Bb + (size_t)(r0) * Kdim + (k0) + c0s,      (Bbuf) + wid * 512);        \
        gll16(Bb + (size_t)(64 + r0) * Kdim + (k0) + c0s, (Bbuf) + 2048 + wid * 512); \
    } while (0)

    unsigned short *A0 = sh, *A1 = sh + 4096, *A2 = sh + 8192;
    unsigned short *B0 = sh + 12288, *B1 = sh + 16384, *B2 = sh + 20480;

    STAGE_G(0, A0, B0);
    STAGE_G(32, A1, B1);
    WAIT_BAR(4);

    for (int kk = 0; kk < nk; ++kk) {
        if (kk + 2 < nk) STAGE_G((kk + 2) << 5, A2, B2);

        bf16x8 af[4], bfr[4];
#pragma unroll
        for (int i = 0; i < 4; ++i) af[i]  = SWZG(A0, wm + i * 16 + ln15, ln4);
#pragma unroll
        for (int i = 0; i < 4; ++i) bfr[i] = SWZG(B0, wn + i * 16 + ln15, ln4);
#pragma unroll
        for (int i = 0; i < 4; ++i)
#pragma unroll
            for (int j = 0; j < 4; ++j)
                acc[i][j] = __builtin_amdgcn_mfma_f32_16x16x32_bf16(af[i], bfr[j], acc[i][j], 0, 0, 0);

        if (kk + 1 < nk) {
            if (kk + 2 < nk) WAIT_BAR(4);
            else             WAIT_BAR(0);
        }
        unsigned short* tA = A0; A0 = A1; A1 = A2; A2 = tA;
        unsigned short* tB = B0; B0 = B1; B1 = B2; B2 = tB;
    }
#undef STAGE_G

#pragma unroll
    for (int i = 0; i < 4; ++i) {
#pragma unroll
        for (int j = 0; j < 4; ++j) {
            const int gmb = m0 + wm + i * 16 + ln4 * 4;
            const int gn  = n0 + wn + j * 16 + ln15;
#pragma unroll
            for (int r = 0; r < 4; ++r)
                C0[(size_t)(gmb + r) * Ndim + gn] = acc[i][j][r] + bias[gn];
        }
    }
}

// ---------------- flash attention, swapped-operand 32x32, 4 waves x 32 q-rows ----------------
// R9's proven structure VERBATIM (76us, VGPR 80): latency/issue-bound local optimum.
template<int NSPLIT>
__global__ __launch_bounds__(256) void attn_kernel(
    const unsigned short* __restrict__ Q, const unsigned short* __restrict__ K,
    const unsigned short* __restrict__ V, unsigned short* __restrict__ O,
    float* __restrict__ Op, float* __restrict__ Ml)
{
    __shared__ unsigned short lds[16384];

    const int t = threadIdx.x, wid = t >> 6, lane = t & 63;
    const int ln31 = lane & 31, lhi = lane >> 5;

    int qtile, bh, split;
    if constexpr (NSPLIT == 2) {
        const int lin = blockIdx.x + blockIdx.y * 32;     // 1280 wgs
        const int nl  = (lin & 7) * 160 + (lin >> 3);
        split = nl & 1; qtile = (nl >> 1) & 15; bh = nl >> 5;
    } else {
        const int lin = blockIdx.x + blockIdx.y * 16;     // 640 wgs
        const int nl  = (lin & 7) * 80 + (lin >> 3);
        split = 0; qtile = nl & 15; bh = nl >> 4;
    }

    const int q0 = qtile * 128;
    const int t00 = split * 1024;
    const int NT  = (NSPLIT == 2) ? 16 : 32;
    const unsigned short* Qh = Q + (size_t)bh * S_ * HD_;
    const unsigned short* Kh = K + (size_t)bh * S_ * HD_;
    const unsigned short* Vh = V + (size_t)bh * HD_ * S_;

    const int srow = t >> 3;
    const int scol = (((t & 7) ^ (srow & 7)) * 8);

#pragma unroll
    for (int j = 0; j < 4; ++j)
        gll16(Qh + (size_t)(q0 + j * 32 + srow) * HD_ + scol,
              lds + 8192 + j * 2048 + wid * 512);
    __syncthreads();

    bf16x8 qf[4];
    {
        const int row = wid * 32 + ln31;
#pragma unroll
        for (int j = 0; j < 4; ++j)
            qf[j] = SWZ(lds + 8192, row, j * 2 + lhi);
    }

    gll16(Kh + (size_t)(t00 + srow) * HD_ + scol,      lds + wid * 512);
    gll16(Kh + (size_t)(t00 + 32 + srow) * HD_ + scol, lds + 2048 + wid * 512);
    gll16(Vh + (size_t)srow * S_ + t00 + scol,         lds + 4096 + wid * 512);
    gll16(Vh + (size_t)(32 + srow) * S_ + t00 + scol,  lds + 4096 + 2048 + wid * 512);
    __syncthreads();

    const unsigned short* Kp = Kh + (size_t)(t00 + 64 + srow) * HD_ + scol;
    const unsigned short* Vp = Vh + (size_t)srow * S_ + t00 + 64 + scol;

    f32x16 ot[2];
#pragma unroll
    for (int r = 0; r < 16; ++r) { ot[0][r] = 0.f; ot[1][r] = 0.f; }
    float m_ = -3.0e38f, l_ = 0.f;

    for (int it = 0; it < NT; ++it) {
        const unsigned short* cb = lds + (it & 1) * 8192;
        if (it + 1 < NT) {
            unsigned short* nb = lds + ((it + 1) & 1) * 8192;
            gll16(Kp,            nb + wid * 512);
            gll16(Kp + 32 * HD_, nb + 2048 + wid * 512);
            gll16(Vp,            nb + 4096 + wid * 512);
            gll16(Vp + 32 * S_,  nb + 4096 + 2048 + wid * 512);
            Kp += 64 * HD_;
            Vp += 64;
        }

        f32x16 st[2];
#pragma unroll
        for (int r = 0; r < 16; ++r) { st[0][r] = 0.f; st[1][r] = 0.f; }
        __builtin_amdgcn_s_setprio(1);
#pragma unroll
        for (int h = 0; h < 2; ++h) {
            const int row = h * 32 + ln31;
#pragma unroll
            for (int j = 0; j < 4; ++j) {
                const bf16x8 kf = SWZ(cb, row, j * 2 + lhi);
                st[h] = __builtin_amdgcn_mfma_f32_32x32x16_bf16(kf, qf[j], st[h], 0, 0, 0);
            }
        }
        __builtin_amdgcn_s_setprio(0);

        float t8[8];
#pragma unroll
        for (int i = 0; i < 8; ++i)
            t8[i] = fmaxf(fmaxf(st[0][i], st[0][i + 8]), fmaxf(st[1][i], st[1][i + 8]));
        const float ta = fmaxf(fmaxf(t8[0], t8[4]), fmaxf(t8[1], t8[5]));
        const float tb = fmaxf(fmaxf(t8[2], t8[6]), fmaxf(t8[3], t8[7]));
        float rm = fmaxf(ta, tb);
        rm = fmaxf(rm, __shfl_xor(rm, 32));

        if (__any(rm - m_ > 8.0f)) {
            const float mn = fmaxf(m_, rm);
            const float sf = fexp2(m_ - mn);
            l_ *= sf;
#pragma unroll
            for (int r = 0; r < 16; ++r) { ot[0][r] *= sf; ot[1][r] *= sf; }
            m_ = mn;
        }

#pragma unroll
        for (int r = 0; r < 16; ++r) {
            st[0][r] = fexp2(st[0][r] - m_);
            st[1][r] = fexp2(st[1][r] - m_);
        }

        {
            float s8[8];
#pragma unroll
            for (int i = 0; i < 8; ++i)
                s8[i] = (st[0][i] + st[0][i + 8]) + (st[1][i] + st[1][i + 8]);
#pragma unroll
            for (int i = 0; i < 4; ++i) s8[i] += s8[i + 4];
            float rs = (s8[0] + s8[1]) + (s8[2] + s8[3]);
            rs += __shfl_xor(rs, 32);
            l_ += rs;
        }

        bf16x8 pa[4];
#pragma unroll
        for (int c = 0; c < 4; ++c) {
            const int hh = c >> 1, rb = (c & 1) * 8;
            const unsigned wA = cvtpk(st[hh][rb + 0], st[hh][rb + 1]);
            const unsigned wB = cvtpk(st[hh][rb + 2], st[hh][rb + 3]);
            const unsigned wC = cvtpk(st[hh][rb + 4], st[hh][rb + 5]);
            const unsigned wD = cvtpk(st[hh][rb + 6], st[hh][rb + 7]);
            auto s0 = __builtin_amdgcn_permlane32_swap(wA, wC, false, false);
            auto s1 = __builtin_amdgcn_permlane32_swap(wB, wD, false, false);
            union { unsigned i[4]; bf16x8 v; } u;
            u.i[0] = s0[0]; u.i[1] = s1[0]; u.i[2] = s0[1]; u.i[3] = s1[1];
            pa[c] = u.v;
        }

        __builtin_amdgcn_s_setprio(1);
#pragma unroll
        for (int h = 0; h < 2; ++h) {
            const int row = h * 32 + ln31;
#pragma unroll
            for (int c = 0; c < 4; ++c) {
                const bf16x8 vf = SWZ(cb + 4096, row, c * 2 + lhi);
                ot[h] = __builtin_amdgcn_mfma_f32_32x32x16_bf16(vf, pa[c], ot[h], 0, 0, 0);
            }
        }
        __builtin_amdgcn_s_setprio(0);

        __syncthreads();
    }

    const int qg = q0 + wid * 32 + ln31;

    if constexpr (NSPLIT == 2) {
        const size_t rowi = (size_t)(split * 40 + bh) * 2048 + qg;
        if (lhi == 0) {
            float2 s; s.x = m_; s.y = l_;
            ((float2*)Ml)[rowi] = s;
        }
        float* Orow = Op + rowi * 64;
#pragma unroll
        for (int h = 0; h < 2; ++h)
#pragma unroll
            for (int g = 0; g < 4; ++g) {
                f32x4 w = {ot[h][g * 4 + 0], ot[h][g * 4 + 1],
                           ot[h][g * 4 + 2], ot[h][g * 4 + 3]};
                *(f32x4*)(Orow + h * 32 + lhi * 4 + g * 8) = w;
            }
    } else {
        const int b = bh / H_, hh = bh % H_;
        const float inv = 1.0f / l_;
        unsigned short* Orow = O + (size_t)(b * S_ + qg) * D_ + hh * HD_;
#pragma unroll
        for (int h = 0; h < 2; ++h)
#pragma unroll
            for (int g = 0; g < 4; ++g) {
                ushort4 w;
                w.x = b2u(ot[h][g * 4 + 0] * inv);
                w.y = b2u(ot[h][g * 4 + 1] * inv);
                w.z = b2u(ot[h][g * 4 + 2] * inv);
                w.w = b2u(ot[h][g * 4 + 3] * inv);
                *(ushort4*)(Orow + h * 32 + lhi * 4 + g * 8) = w;
            }
    }
}

// ---------------- combine the two KV-split halves ----------------
__global__ __launch_bounds__(256) void attn_combine(
    const float* __restrict__ Op, const float* __restrict__ Ml,
    unsigned short* __restrict__ O)
{
    const int gid = blockIdx.x * 256 + threadIdx.x;
    const int row = gid >> 4;
    const int c   = (gid & 15) * 4;
    const int bh = row >> 11, qg = row & 2047;

    const float2 s0 = ((const float2*)Ml)[row];
    const float2 s1 = ((const float2*)Ml)[81920 + row];
    const float mm = fmaxf(s0.x, s1.x);
    const float a0 = fexp2(s0.x - mm), a1 = fexp2(s1.x - mm);
    const float inv = 1.0f / (a0 * s0.y + a1 * s1.y);

    const f32x4 o0 = *(const f32x4*)(Op + (size_t)row * 64 + c);
    const f32x4 o1 = *(const f32x4*)(Op + (size_t)(81920 + row) * 64 + c);

    const int b = bh / H_, hh = bh % H_;
    ushort4 w;
    w.x = b2u((a0 * o0[0] + a1 * o1[0]) * inv);
    w.y = b2u((a0 * o0[1] + a1 * o1[1]) * inv);
    w.z = b2u((a0 * o0[2] + a1 * o1[2]) * inv);
    w.w = b2u((a0 * o0[3] + a1 * o1[3]) * inv);
    *(ushort4*)(O + (size_t)(b * S_ + qg) * D_ + hh * HD_ + c) = w;
}

extern "C" void kernel_launch(void* const* d_in, const int* in_sizes, int n_in,
                              void* d_out, int out_size, void* d_ws, size_t ws_size,
                              hipStream_t stream)
{
    const float* hid = (const float*)d_in[0];
    const float* Wq  = (const float*)d_in[1];
    const float* Wk  = (const float*)d_in[2];
    const float* Wv  = (const float*)d_in[3];
    const float* Wo  = (const float*)d_in[4];
    const float* bo  = (const float*)d_in[5];
    float* out = (float*)d_out;

    char* ws = (char*)d_ws;
    unsigned short* Xb  = (unsigned short*)(ws);                    // 4096x1280 bf16
    unsigned short* Wt  = (unsigned short*)(ws + 10485760);         // 4x 1280x1280 bf16 (transposed)
    unsigned short* Qb  = (unsigned short*)(ws + 23592960);         // [b][h][s][64]
    unsigned short* Kb  = (unsigned short*)(ws + 34078720);         // [b][h][s][64]
    unsigned short* Vb  = (unsigned short*)(ws + 44564480);         // [b][h][64][s]
    unsigned short* Ob  = (unsigned short*)(ws + 55050240);         // [4096][1280]
    float*          Opart = (float*)(ws + 65536000);                // [2][40][2048][64] fp32
    float*          Mpart = (float*)(ws + 107479040);               // [2][40][2048] float2
    const size_t ws_need = 108789760ull;

    // fused cast + weight-transpose prep
    prep_kernel<<<6720, 256, 0, stream>>>(hid, Xb, Wq, Wk, Wv, Wo, Wt);

    const float SCALE_Q = 0.125f * 1.44269504088896340736f;  // sm_scale * log2(e)

    // fused QKV projection: Bt = [Wq^T; Wk^T; Wv^T] contiguous = [3840][1280]
    // 256x128 tiles, 8 waves: 480 blocks = one scheduling round at 2 blocks/CU.
    gemm_qkv<<<dim3(30, 16), 512, 0, stream>>>(Xb, Wt, Qb, Kb, Vb, D_, SCALE_Q);

    if (ws_size >= ws_need) {
        attn_kernel<2><<<dim3(32, 40), 256, 0, stream>>>(Qb, Kb, Vb, Ob, Opart, Mpart);
        attn_combine<<<5120, 256, 0, stream>>>(Opart, Mpart, Ob);
    } else {
        attn_kernel<1><<<dim3(16, 40), 256, 0, stream>>>(Qb, Kb, Vb, Ob, nullptr, nullptr);
    }

    gemm_bf16<<<dim3(10, 32), 256, 0, stream>>>(Ob, Wt + 3 * 1638400, out, bo, D_, D_);
}

// Round 18
// 169.819 us; speedup vs baseline: 1.2125x; 1.0132x over previous
//
#include <hip/hip_runtime.h>
#include <hip/hip_bf16.h>

typedef __bf16 bf16x8 __attribute__((ext_vector_type(8)));
typedef float  f32x4  __attribute__((ext_vector_type(4)));
typedef float  f32x16 __attribute__((ext_vector_type(16)));

#define H_  20
#define S_  2048
#define D_  1280
#define HD_ 64
#define M_  4096

__device__ __forceinline__ unsigned short f2bf(float f) {
    union { float f; unsigned int u; } v; v.f = f;
    return (unsigned short)((v.u + 0x7FFFu + ((v.u >> 16) & 1u)) >> 16);
}

__device__ __forceinline__ unsigned short b2u(float f) {
    union { __bf16 b; unsigned short u; } v; v.b = (__bf16)f; return v.u;
}

__device__ __forceinline__ float bf2f(unsigned short u) {
    union { unsigned u; float f; } v; v.u = ((unsigned)u) << 16; return v.f;
}

// bare v_exp_f32 (libm exp2f is a ~15-instr libcall)
__device__ __forceinline__ float fexp2(float x) {
    return __builtin_amdgcn_exp2f(x);
}

// packed f32x2 -> bf16x2, single HW instr
__device__ __forceinline__ unsigned cvtpk(float lo, float hi) {
    unsigned r;
    asm("v_cvt_pk_bf16_f32 %0, %1, %2" : "=v"(r) : "v"(lo), "v"(hi));
    return r;
}

__device__ __forceinline__ void gll16(const void* g, void* l) {
    __builtin_amdgcn_global_load_lds(
        (const __attribute__((address_space(1))) unsigned int*)g,
        (__attribute__((address_space(3))) unsigned int*)l, 16, 0, 0);
}

// counted-vmcnt barrier (T4): leave N loads in flight, raw barrier (no drain).
#define WAIT_BAR(N) asm volatile("s_waitcnt vmcnt(" #N ")\n\ts_barrier" ::: "memory")

// attn LDS (128B rows, 8x16B granules): phys granule = g ^ (row&7)
#define SWZ(base, row, g) \
    (*(const bf16x8*)((base) + (row) * 64 + (((g) ^ ((row) & 7)) * 8)))

// gemm LDS (64B rows, 4x16B granules): phys granule = g ^ ((row>>1)&3)
#define SWZG(base, row, g) \
    (*(const bf16x8*)((base) + (row) * 32 + ((((g) ^ (((row) >> 1) & 3)) * 8))))

// ---------------- fused prep: cast X (blocks 0..5119) + transpose W (5120..6719) ----------------
__global__ __launch_bounds__(256) void prep_kernel(
    const float* __restrict__ X, unsigned short* __restrict__ Xb,
    const float* __restrict__ W0, const float* __restrict__ W1,
    const float* __restrict__ W2, const float* __restrict__ W3,
    unsigned short* __restrict__ Wt)
{
    __shared__ unsigned short tile[64][65];
    const int blk = blockIdx.x;
    if (blk < 5120) {
        const int i = (blk * 256 + threadIdx.x) * 4;
        const float4 v = *(const float4*)(X + i);
        ushort4 o;
        o.x = f2bf(v.x); o.y = f2bf(v.y); o.z = f2bf(v.z); o.w = f2bf(v.w);
        *(ushort4*)(Xb + i) = o;
    } else {
        const int r = blk - 5120;
        const int wz = r / 400, rem = r - wz * 400;
        const int n0 = (rem % 20) * 64, k0 = (rem / 20) * 64;
        const float* src = (wz == 0) ? W0 : (wz == 1) ? W1 : (wz == 2) ? W2 : W3;
        unsigned short* dst = Wt + (size_t)wz * D_ * D_;
        const int tx = threadIdx.x & 63, ty = threadIdx.x >> 6;
#pragma unroll
        for (int i = 0; i < 16; ++i) {
            const int row = ty * 16 + i;
            tile[row][tx] = f2bf(src[(size_t)(k0 + row) * D_ + n0 + tx]);
        }
        __syncthreads();
#pragma unroll
        for (int i = 0; i < 16; ++i) {
            const int row = ty * 16 + i;
            dst[(size_t)(n0 + row) * D_ + k0 + tx] = tile[tx][row];
        }
    }
}

// ---------------- 256x128 QKV GEMM, 8 waves: {Q scaled, K, Vt} epilogue ----------------
// One scheduling round (480 blocks <= 2/CU x 256), 16 waves/CU, 3-buffer
// counted-vmcnt pipeline (3 gll16/step, WAIT_BAR(3)). Per-wave 64x64 acc[4][4].
__global__ __launch_bounds__(512) void gemm_qkv(
    const unsigned short* __restrict__ A, const unsigned short* __restrict__ Bt,
    unsigned short* __restrict__ C0, unsigned short* __restrict__ C1,
    unsigned short* __restrict__ C2, int Kdim, float oscale)
{
    __shared__ unsigned short sh[36864];  // A0,A1,A2 @0 (8192 el each); B0,B1,B2 @24576 (4096 el each)
    const int t = threadIdx.x;
    const int wid = t >> 6, lane = t & 63;

    const int lin = blockIdx.x + blockIdx.y * gridDim.x;
    const int xcd = lin & 7, q = lin >> 3;              // q 0..59
    const int bx = q >> 1, by = xcd * 2 + (q & 1);      // bx 0..29, by 0..15

    const int m0 = by * 256, n0 = bx * 128;
    const int wm = (wid >> 1) * 64, wn = (wid & 1) * 64;
    const int ln15 = lane & 15, ln4 = lane >> 4;

    f32x4 acc[4][4];
#pragma unroll
    for (int i = 0; i < 4; ++i)
#pragma unroll
        for (int j = 0; j < 4; ++j) acc[i][j] = (f32x4){0.f, 0.f, 0.f, 0.f};

    const int r0 = t >> 2;                                   // staging row 0..127
    const int c0s = (((t & 3) ^ ((r0 >> 1) & 3)) * 8);       // inverse-swizzled src granule
    const unsigned short* Ab = A + (size_t)m0 * Kdim;
    const unsigned short* Bb = Bt + (size_t)n0 * Kdim;
    const int nk = Kdim >> 5;

#define STAGE_Q(k0, Abuf, Bbuf)                                                        \
    do {                                                                               \
        gll16(Ab + (size_t)(r0) * Kdim + (k0) + c0s,       (Abuf) + wid * 512);        \
        gll16(Ab + (size_t)(128 + r0) * Kdim + (k0) + c0s, (Abuf) + 4096 + wid * 512); \
        gll16(Bb + (size_t)(r0) * Kdim + (k0) + c0s,       (Bbuf) + wid * 512);        \
    } while (0)

    unsigned short *A0 = sh, *A1 = sh + 8192, *A2 = sh + 16384;
    unsigned short *B0 = sh + 24576, *B1 = sh + 28672, *B2 = sh + 32768;

    STAGE_Q(0, A0, B0);
    STAGE_Q(32, A1, B1);
    WAIT_BAR(3);

    for (int kk = 0; kk < nk; ++kk) {
        if (kk + 2 < nk) STAGE_Q((kk + 2) << 5, A2, B2);

        bf16x8 af[4], bfr[4];
#pragma unroll
        for (int i = 0; i < 4; ++i) af[i]  = SWZG(A0, wm + i * 16 + ln15, ln4);
#pragma unroll
        for (int i = 0; i < 4; ++i) bfr[i] = SWZG(B0, wn + i * 16 + ln15, ln4);
#pragma unroll
        for (int i = 0; i < 4; ++i)
#pragma unroll
            for (int j = 0; j < 4; ++j)
                acc[i][j] = __builtin_amdgcn_mfma_f32_16x16x32_bf16(af[i], bfr[j], acc[i][j], 0, 0, 0);

        if (kk + 1 < nk) {
            if (kk + 2 < nk) WAIT_BAR(3);
            else             WAIT_BAR(0);
        }
        unsigned short* tA = A0; A0 = A1; A1 = A2; A2 = tA;
        unsigned short* tB = B0; B0 = B1; B1 = B2; B2 = tB;
    }
#undef STAGE_Q

    // epilogue: fused QKV scatter
#pragma unroll
    for (int i = 0; i < 4; ++i) {
#pragma unroll
        for (int j = 0; j < 4; ++j) {
            const int gmb = m0 + wm + i * 16 + ln4 * 4;
            const int gn  = n0 + wn + j * 16 + ln15;
            const int which = gn / 1280;
            const int nn = gn - which * 1280;
            const int h = nn >> 6, d = nn & 63;
#pragma unroll
            for (int r = 0; r < 4; ++r) {
                float val = acc[i][j][r];
                const int m = gmb + r;
                const int b = m >> 11, s = m & 2047;
                if (which == 0) val *= oscale;
                size_t idx;
                unsigned short* dst;
                if (which == 2) { idx = ((size_t)(b * H_ + h) * HD_ + d) * S_ + s; dst = C2; }
                else            { idx = ((size_t)(b * H_ + h) * S_ + s) * HD_ + d; dst = (which == 0) ? C0 : C1; }
                dst[idx] = f2bf(val);
            }
        }
    }
}

// ---------------- 128x128 bf16 GEMM (final projection, mode-3 f32 + bias) ----------------
__global__ __launch_bounds__(256) void gemm_bf16(
    const unsigned short* __restrict__ A, const unsigned short* __restrict__ Bt,
    float* __restrict__ C0, const float* __restrict__ bias, int Kdim, int Ndim)
{
    __shared__ unsigned short sh[24576];   // A0,A1,A2 @0; B0,B1,B2 @12288 (48KB)
    const int t = threadIdx.x;
    const int wid = t >> 6, lane = t & 63;

    const int lin = blockIdx.x + blockIdx.y * gridDim.x;
    const int xcd = lin & 7, q = lin >> 3;
    const int bx = q >> 2, by = xcd * 4 + (q & 3);

    const int m0 = by * 128, n0 = bx * 128;
    const int wm = (wid >> 1) * 64, wn = (wid & 1) * 64;
    const int ln15 = lane & 15, ln4 = lane >> 4;

    f32x4 acc[4][4];
#pragma unroll
    for (int i = 0; i < 4; ++i)
#pragma unroll
        for (int j = 0; j < 4; ++j) acc[i][j] = (f32x4){0.f, 0.f, 0.f, 0.f};

    const int r0 = t >> 2;
    const int c0s = (((t & 3) ^ ((r0 >> 1) & 3)) * 8);
    const unsigned short* Ab = A + (size_t)m0 * Kdim;
    const unsigned short* Bb = Bt + (size_t)n0 * Kdim;
    const int nk = Kdim >> 5;

#define STAGE_G(k0, Abuf, Bbuf)                                           \
    do {                                                                  \
        gll16(Ab + (size_t)(r0) * Kdim + (k0) + c0s,      (Abuf) + wid * 512);        \
        gll16(Ab + (size_t)(64 + r0) * Kdim + (k0) + c0s, (Abuf) + 2048 + wid * 512); \
        gll16(Bb + (size_t)(r0) * Kdim + (k0) + c0s,      (Bbuf) + wid * 512);        \
        gll16(Bb + (size_t)(64 + r0) * Kdim + (k0) + c0s, (Bbuf) + 2048 + wid * 512); \
    } while (0)

    unsigned short *A0 = sh, *A1 = sh + 4096, *A2 = sh + 8192;
    unsigned short *B0 = sh + 12288, *B1 = sh + 16384, *B2 = sh + 20480;

    STAGE_G(0, A0, B0);
    STAGE_G(32, A1, B1);
    WAIT_BAR(4);

    for (int kk = 0; kk < nk; ++kk) {
        if (kk + 2 < nk) STAGE_G((kk + 2) << 5, A2, B2);

        bf16x8 af[4], bfr[4];
#pragma unroll
        for (int i = 0; i < 4; ++i) af[i]  = SWZG(A0, wm + i * 16 + ln15, ln4);
#pragma unroll
        for (int i = 0; i < 4; ++i) bfr[i] = SWZG(B0, wn + i * 16 + ln15, ln4);
#pragma unroll
        for (int i = 0; i < 4; ++i)
#pragma unroll
            for (int j = 0; j < 4; ++j)
                acc[i][j] = __builtin_amdgcn_mfma_f32_16x16x32_bf16(af[i], bfr[j], acc[i][j], 0, 0, 0);

        if (kk + 1 < nk) {
            if (kk + 2 < nk) WAIT_BAR(4);
            else             WAIT_BAR(0);
        }
        unsigned short* tA = A0; A0 = A1; A1 = A2; A2 = tA;
        unsigned short* tB = B0; B0 = B1; B1 = B2; B2 = tB;
    }
#undef STAGE_G

#pragma unroll
    for (int i = 0; i < 4; ++i) {
#pragma unroll
        for (int j = 0; j < 4; ++j) {
            const int gmb = m0 + wm + i * 16 + ln4 * 4;
            const int gn  = n0 + wn + j * 16 + ln15;
#pragma unroll
            for (int r = 0; r < 4; ++r)
                C0[(size_t)(gmb + r) * Ndim + gn] = acc[i][j][r] + bias[gn];
        }
    }
}

// ---------------- flash attention, swapped-operand 32x32, 4 waves x 32 q-rows ----------------
// R9's proven structure; NSPLIT=2 partials now written as BF16 (halves the 42MB
// partial-write + combine-read traffic; (m,l) stats stay fp32).
template<int NSPLIT>
__global__ __launch_bounds__(256) void attn_kernel(
    const unsigned short* __restrict__ Q, const unsigned short* __restrict__ K,
    const unsigned short* __restrict__ V, unsigned short* __restrict__ O,
    unsigned short* __restrict__ Op, float* __restrict__ Ml)
{
    __shared__ unsigned short lds[16384];

    const int t = threadIdx.x, wid = t >> 6, lane = t & 63;
    const int ln31 = lane & 31, lhi = lane >> 5;

    int qtile, bh, split;
    if constexpr (NSPLIT == 2) {
        const int lin = blockIdx.x + blockIdx.y * 32;     // 1280 wgs
        const int nl  = (lin & 7) * 160 + (lin >> 3);
        split = nl & 1; qtile = (nl >> 1) & 15; bh = nl >> 5;
    } else {
        const int lin = blockIdx.x + blockIdx.y * 16;     // 640 wgs
        const int nl  = (lin & 7) * 80 + (lin >> 3);
        split = 0; qtile = nl & 15; bh = nl >> 4;
    }

    const int q0 = qtile * 128;
    const int t00 = split * 1024;
    const int NT  = (NSPLIT == 2) ? 16 : 32;
    const unsigned short* Qh = Q + (size_t)bh * S_ * HD_;
    const unsigned short* Kh = K + (size_t)bh * S_ * HD_;
    const unsigned short* Vh = V + (size_t)bh * HD_ * S_;

    const int srow = t >> 3;
    const int scol = (((t & 7) ^ (srow & 7)) * 8);

#pragma unroll
    for (int j = 0; j < 4; ++j)
        gll16(Qh + (size_t)(q0 + j * 32 + srow) * HD_ + scol,
              lds + 8192 + j * 2048 + wid * 512);
    __syncthreads();

    bf16x8 qf[4];
    {
        const int row = wid * 32 + ln31;
#pragma unroll
        for (int j = 0; j < 4; ++j)
            qf[j] = SWZ(lds + 8192, row, j * 2 + lhi);
    }

    gll16(Kh + (size_t)(t00 + srow) * HD_ + scol,      lds + wid * 512);
    gll16(Kh + (size_t)(t00 + 32 + srow) * HD_ + scol, lds + 2048 + wid * 512);
    gll16(Vh + (size_t)srow * S_ + t00 + scol,         lds + 4096 + wid * 512);
    gll16(Vh + (size_t)(32 + srow) * S_ + t00 + scol,  lds + 4096 + 2048 + wid * 512);
    __syncthreads();

    const unsigned short* Kp = Kh + (size_t)(t00 + 64 + srow) * HD_ + scol;
    const unsigned short* Vp = Vh + (size_t)srow * S_ + t00 + 64 + scol;

    f32x16 ot[2];
#pragma unroll
    for (int r = 0; r < 16; ++r) { ot[0][r] = 0.f; ot[1][r] = 0.f; }
    float m_ = -3.0e38f, l_ = 0.f;

    for (int it = 0; it < NT; ++it) {
        const unsigned short* cb = lds + (it & 1) * 8192;
        if (it + 1 < NT) {
            unsigned short* nb = lds + ((it + 1) & 1) * 8192;
            gll16(Kp,            nb + wid * 512);
            gll16(Kp + 32 * HD_, nb + 2048 + wid * 512);
            gll16(Vp,            nb + 4096 + wid * 512);
            gll16(Vp + 32 * S_,  nb + 4096 + 2048 + wid * 512);
            Kp += 64 * HD_;
            Vp += 64;
        }

        f32x16 st[2];
#pragma unroll
        for (int r = 0; r < 16; ++r) { st[0][r] = 0.f; st[1][r] = 0.f; }
        __builtin_amdgcn_s_setprio(1);
#pragma unroll
        for (int h = 0; h < 2; ++h) {
            const int row = h * 32 + ln31;
#pragma unroll
            for (int j = 0; j < 4; ++j) {
                const bf16x8 kf = SWZ(cb, row, j * 2 + lhi);
                st[h] = __builtin_amdgcn_mfma_f32_32x32x16_bf16(kf, qf[j], st[h], 0, 0, 0);
            }
        }
        __builtin_amdgcn_s_setprio(0);

        float t8[8];
#pragma unroll
        for (int i = 0; i < 8; ++i)
            t8[i] = fmaxf(fmaxf(st[0][i], st[0][i + 8]), fmaxf(st[1][i], st[1][i + 8]));
        const float ta = fmaxf(fmaxf(t8[0], t8[4]), fmaxf(t8[1], t8[5]));
        const float tb = fmaxf(fmaxf(t8[2], t8[6]), fmaxf(t8[3], t8[7]));
        float rm = fmaxf(ta, tb);
        rm = fmaxf(rm, __shfl_xor(rm, 32));

        if (__any(rm - m_ > 8.0f)) {
            const float mn = fmaxf(m_, rm);
            const float sf = fexp2(m_ - mn);
            l_ *= sf;
#pragma unroll
            for (int r = 0; r < 16; ++r) { ot[0][r] *= sf; ot[1][r] *= sf; }
            m_ = mn;
        }

#pragma unroll
        for (int r = 0; r < 16; ++r) {
            st[0][r] = fexp2(st[0][r] - m_);
            st[1][r] = fexp2(st[1][r] - m_);
        }

        {
            float s8[8];
#pragma unroll
            for (int i = 0; i < 8; ++i)
                s8[i] = (st[0][i] + st[0][i + 8]) + (st[1][i] + st[1][i + 8]);
#pragma unroll
            for (int i = 0; i < 4; ++i) s8[i] += s8[i + 4];
            float rs = (s8[0] + s8[1]) + (s8[2] + s8[3]);
            rs += __shfl_xor(rs, 32);
            l_ += rs;
        }

        bf16x8 pa[4];
#pragma unroll
        for (int c = 0; c < 4; ++c) {
            const int hh = c >> 1, rb = (c & 1) * 8;
            const unsigned wA = cvtpk(st[hh][rb + 0], st[hh][rb + 1]);
            const unsigned wB = cvtpk(st[hh][rb + 2], st[hh][rb + 3]);
            const unsigned wC = cvtpk(st[hh][rb + 4], st[hh][rb + 5]);
            const unsigned wD = cvtpk(st[hh][rb + 6], st[hh][rb + 7]);
            auto s0 = __builtin_amdgcn_permlane32_swap(wA, wC, false, false);
            auto s1 = __builtin_amdgcn_permlane32_swap(wB, wD, false, false);
            union { unsigned i[4]; bf16x8 v; } u;
            u.i[0] = s0[0]; u.i[1] = s1[0]; u.i[2] = s0[1]; u.i[3] = s1[1];
            pa[c] = u.v;
        }

        __builtin_amdgcn_s_setprio(1);
#pragma unroll
        for (int h = 0; h < 2; ++h) {
            const int row = h * 32 + ln31;
#pragma unroll
            for (int c = 0; c < 4; ++c) {
                const bf16x8 vf = SWZ(cb + 4096, row, c * 2 + lhi);
                ot[h] = __builtin_amdgcn_mfma_f32_32x32x16_bf16(vf, pa[c], ot[h], 0, 0, 0);
            }
        }
        __builtin_amdgcn_s_setprio(0);

        __syncthreads();
    }

    const int qg = q0 + wid * 32 + ln31;

    if constexpr (NSPLIT == 2) {
        // ---- write unnormalized BF16 partials + fp32 (m,l) stats ----
        const size_t rowi = (size_t)(split * 40 + bh) * 2048 + qg;
        if (lhi == 0) {
            float2 s; s.x = m_; s.y = l_;
            ((float2*)Ml)[rowi] = s;
        }
        unsigned short* Orow = Op + rowi * 64;
#pragma unroll
        for (int h = 0; h < 2; ++h)
#pragma unroll
            for (int g = 0; g < 4; ++g) {
                ushort4 w;
                w.x = b2u(ot[h][g * 4 + 0]);
                w.y = b2u(ot[h][g * 4 + 1]);
                w.z = b2u(ot[h][g * 4 + 2]);
                w.w = b2u(ot[h][g * 4 + 3]);
                *(ushort4*)(Orow + h * 32 + lhi * 4 + g * 8) = w;
            }
    } else {
        const int b = bh / H_, hh = bh % H_;
        const float inv = 1.0f / l_;
        unsigned short* Orow = O + (size_t)(b * S_ + qg) * D_ + hh * HD_;
#pragma unroll
        for (int h = 0; h < 2; ++h)
#pragma unroll
            for (int g = 0; g < 4; ++g) {
                ushort4 w;
                w.x = b2u(ot[h][g * 4 + 0] * inv);
                w.y = b2u(ot[h][g * 4 + 1] * inv);
                w.z = b2u(ot[h][g * 4 + 2] * inv);
                w.w = b2u(ot[h][g * 4 + 3] * inv);
                *(ushort4*)(Orow + h * 32 + lhi * 4 + g * 8) = w;
            }
    }
}

// ---------------- combine the two KV-split halves (bf16 partials) ----------------
__global__ __launch_bounds__(256) void attn_combine(
    const unsigned short* __restrict__ Op, const float* __restrict__ Ml,
    unsigned short* __restrict__ O)
{
    const int gid = blockIdx.x * 256 + threadIdx.x;
    const int row = gid >> 4;
    const int c   = (gid & 15) * 4;
    const int bh = row >> 11, qg = row & 2047;

    const float2 s0 = ((const float2*)Ml)[row];
    const float2 s1 = ((const float2*)Ml)[81920 + row];
    const float mm = fmaxf(s0.x, s1.x);
    const float a0 = fexp2(s0.x - mm), a1 = fexp2(s1.x - mm);
    const float inv = 1.0f / (a0 * s0.y + a1 * s1.y);

    const ushort4 u0 = *(const ushort4*)(Op + (size_t)row * 64 + c);
    const ushort4 u1 = *(const ushort4*)(Op + (size_t)(81920 + row) * 64 + c);

    const int b = bh / H_, hh = bh % H_;
    ushort4 w;
    w.x = b2u((a0 * bf2f(u0.x) + a1 * bf2f(u1.x)) * inv);
    w.y = b2u((a0 * bf2f(u0.y) + a1 * bf2f(u1.y)) * inv);
    w.z = b2u((a0 * bf2f(u0.z) + a1 * bf2f(u1.z)) * inv);
    w.w = b2u((a0 * bf2f(u0.w) + a1 * bf2f(u1.w)) * inv);
    *(ushort4*)(O + (size_t)(b * S_ + qg) * D_ + hh * HD_ + c) = w;
}

extern "C" void kernel_launch(void* const* d_in, const int* in_sizes, int n_in,
                              void* d_out, int out_size, void* d_ws, size_t ws_size,
                              hipStream_t stream)
{
    const float* hid = (const float*)d_in[0];
    const float* Wq  = (const float*)d_in[1];
    const float* Wk  = (const float*)d_in[2];
    const float* Wv  = (const float*)d_in[3];
    const float* Wo  = (const float*)d_in[4];
    const float* bo  = (const float*)d_in[5];
    float* out = (float*)d_out;

    char* ws = (char*)d_ws;
    unsigned short* Xb  = (unsigned short*)(ws);                    // 4096x1280 bf16
    unsigned short* Wt  = (unsigned short*)(ws + 10485760);         // 4x 1280x1280 bf16 (transposed)
    unsigned short* Qb  = (unsigned short*)(ws + 23592960);         // [b][h][s][64]
    unsigned short* Kb  = (unsigned short*)(ws + 34078720);         // [b][h][s][64]
    unsigned short* Vb  = (unsigned short*)(ws + 44564480);         // [b][h][64][s]
    unsigned short* Ob  = (unsigned short*)(ws + 55050240);         // [4096][1280]
    unsigned short* Opart = (unsigned short*)(ws + 65536000);       // [2][40][2048][64] bf16
    float*          Mpart = (float*)(ws + 107479040);               // [2][40][2048] float2
    const size_t ws_need = 108789760ull;

    // fused cast + weight-transpose prep
    prep_kernel<<<6720, 256, 0, stream>>>(hid, Xb, Wq, Wk, Wv, Wo, Wt);

    const float SCALE_Q = 0.125f * 1.44269504088896340736f;  // sm_scale * log2(e)

    // fused QKV projection: 256x128 tiles, 8 waves, one scheduling round.
    gemm_qkv<<<dim3(30, 16), 512, 0, stream>>>(Xb, Wt, Qb, Kb, Vb, D_, SCALE_Q);

    if (ws_size >= ws_need) {
        attn_kernel<2><<<dim3(32, 40), 256, 0, stream>>>(Qb, Kb, Vb, Ob, Opart, Mpart);
        attn_combine<<<5120, 256, 0, stream>>>(Opart, Mpart, Ob);
    } else {
        attn_kernel<1><<<dim3(16, 40), 256, 0, stream>>>(Qb, Kb, Vb, Ob, nullptr, nullptr);
    }

    gemm_bf16<<<dim3(10, 32), 256, 0, stream>>>(Ob, Wt + 3 * 1638400, out, bo, D_, D_);
}